// Round 2
// baseline (131.322 us; speedup 1.0000x reference)
//
#include <hip/hip_runtime.h>

// NeighborPruning: LayerNorm over a size-1 axis makes every score identically
// ln_beta. All regular edges tie; stable lexsort => per-dst top-3 = the 3
// smallest original edge indices among regular (non-self-loop) edges.
// Self loops kept unconditionally.
//
// R5 structure — eliminate global atomics (np_insert was device-scope-CAS
// latency-bound at 1 wave/SIMD occupancy):
//  1) np_write — full grid over E/4: score=beta, keep=self?1:0, int4/float4
//     vectorized streaming (~1.5us).
//  2) np_scan  — 512 blocks = 32 dst-ranges x 16 edge-segments. Each block
//     scans its segment's dst[] with int4 loads (L2-broadcast across ranges:
//     32 x 1.6MB = 51MB L2, ~13MB HBM), keeps top-3 per owned dst in LDS
//     (packed u64, LDS CAS — ~780 hits/block, near-zero contention), then
//     flushes W=ceil(N/32) slots to workspace (6.4MB, coalesced).
//  3) np_merge — one thread per dst: merge 16 partial triples (coalesced
//     reads), scatter keep=1 to the <=3 winners.
//
// Workspace: NBLK * W * 8B = 512 * 1563 * 8 = 6.4 MB (<< ws_size).
// Edge ids fit 21 bits (E = 400000 < 2^21).

#define SENT21 0x1FFFFFu
#define RANGES 32   // dst ranges (power of 2; W*8B LDS per block)
#define SEGS   16   // edge segments
#define NBLK   (RANGES * SEGS)

__device__ __forceinline__ unsigned long long pack3(unsigned a, unsigned b, unsigned c) {
    return ((unsigned long long)a << 42) | ((unsigned long long)b << 21) | (unsigned long long)c;
}

// Monotone top-3 insert into an LDS slot. Fields only decrease => stale plain
// reads are direction-safe (an old value has a LARGER s2, so we never wrongly
// skip; the CAS retry corrects).
__device__ __forceinline__ void lds_insert(unsigned long long* slot, unsigned v) {
    unsigned long long cur = *slot;
    while (v < ((unsigned)cur & SENT21)) {           // v < s2 ?
        unsigned s0 = (unsigned)(cur >> 42) & SENT21;
        unsigned s1 = (unsigned)(cur >> 21) & SENT21;
        unsigned n0, n1, n2;
        if (v < s0)      { n0 = v;  n1 = s0; n2 = s1; }
        else if (v < s1) { n0 = s0; n1 = v;  n2 = s1; }
        else             { n0 = s0; n1 = s1; n2 = v;  }
        unsigned long long prev = atomicCAS(slot, cur, pack3(n0, n1, n2));
        if (prev == cur) break;                      // installed
        cur = prev;                                  // lost race; recheck
    }
}

// Streaming outputs: scores = beta, keep = self-loop ? 1 : 0.
__global__ void np_write(const int* __restrict__ src,
                         const int* __restrict__ dst,
                         const float* __restrict__ ln_beta,
                         float* __restrict__ keep_out,
                         float* __restrict__ score_out, int E) {
    int e = (blockIdx.x * blockDim.x + threadIdx.x) * 4;
    if (e >= E) return;
    float beta = ln_beta[0];
    if (e + 4 <= E) {
        int4 s4 = *reinterpret_cast<const int4*>(src + e);
        int4 d4 = *reinterpret_cast<const int4*>(dst + e);
        float4 k4 = make_float4(s4.x == d4.x ? 1.f : 0.f,
                                s4.y == d4.y ? 1.f : 0.f,
                                s4.z == d4.z ? 1.f : 0.f,
                                s4.w == d4.w ? 1.f : 0.f);
        *reinterpret_cast<float4*>(keep_out + e)  = k4;
        *reinterpret_cast<float4*>(score_out + e) = make_float4(beta, beta, beta, beta);
    } else {
        for (int i = e; i < E; ++i) {
            keep_out[i]  = (src[i] == dst[i]) ? 1.f : 0.f;
            score_out[i] = beta;
        }
    }
}

// Block (r, sg): scan segment sg's dst[], keep LDS top-3 for dst range r,
// flush packed slots to partials[blockIdx][0..W).
__global__ void np_scan(const int* __restrict__ src,
                        const int* __restrict__ dst,
                        unsigned long long* __restrict__ partials,
                        int E, int W, int segLen) {
    extern __shared__ unsigned long long lsl[];
    const int r  = blockIdx.x & (RANGES - 1);
    const int sg = blockIdx.x >> 5;                  // log2(RANGES) = 5
    const int lo = r * W;

    for (int w = threadIdx.x; w < W; w += blockDim.x) lsl[w] = ~0ULL;
    __syncthreads();

    const int e0 = sg * segLen;
    const int e1 = min(E, e0 + segLen);

    int e = e0 + (int)threadIdx.x * 4;
    for (; e + 3 < e1; e += (int)blockDim.x * 4) {
        int4 d4 = *reinterpret_cast<const int4*>(dst + e);
        #pragma unroll
        for (int k = 0; k < 4; ++k) {
            int d = (&d4.x)[k];
            unsigned rel = (unsigned)(d - lo);
            if (rel < (unsigned)W) {                 // ~3% hit rate
                int ei = e + k;
                if (src[ei] != d)                    // exclude self loops
                    lds_insert(&lsl[rel], (unsigned)ei);
            }
        }
    }
    // scalar tail (only the one straddling window when E % 4 != 0)
    for (; e < e1; ++e) {
        int d = dst[e];
        unsigned rel = (unsigned)(d - lo);
        if (rel < (unsigned)W && src[e] != d)
            lds_insert(&lsl[rel], (unsigned)e);
    }

    __syncthreads();
    unsigned long long* out = partials + (size_t)blockIdx.x * (size_t)W;
    for (int w = threadIdx.x; w < W; w += blockDim.x) out[w] = lsl[w];
}

// One thread per dst: merge SEGS sorted triples, scatter keep=1 to winners.
__global__ void np_merge(const unsigned long long* __restrict__ partials,
                         float* __restrict__ keep_out, int N, int W) {
    int d = blockIdx.x * blockDim.x + threadIdx.x;
    if (d >= N) return;
    int r   = d / W;
    int rel = d - r * W;
    unsigned t0 = SENT21, t1 = SENT21, t2 = SENT21;
    for (int sg = 0; sg < SEGS; ++sg) {
        unsigned long long st = partials[(size_t)(sg * RANGES + r) * (size_t)W + rel];
        unsigned a0 = (unsigned)(st >> 42) & SENT21;
        if (a0 >= t2) continue;                      // sorted triple: all >= t2
        if (a0 < t0)      { t2 = t1; t1 = t0; t0 = a0; }
        else if (a0 < t1) { t2 = t1; t1 = a0; }
        else              { t2 = a0; }
        unsigned a1 = (unsigned)(st >> 21) & SENT21;
        if (a1 >= t2) continue;
        if (a1 < t0)      { t2 = t1; t1 = t0; t0 = a1; }
        else if (a1 < t1) { t2 = t1; t1 = a1; }
        else              { t2 = a1; }
        unsigned a2 = (unsigned)st & SENT21;
        if (a2 >= t2) continue;
        if (a2 < t0)      { t2 = t1; t1 = t0; t0 = a2; }
        else if (a2 < t1) { t2 = t1; t1 = a2; }
        else              { t2 = a2; }
    }
    if (t0 != SENT21) keep_out[t0] = 1.f;
    if (t1 != SENT21) keep_out[t1] = 1.f;
    if (t2 != SENT21) keep_out[t2] = 1.f;
}

extern "C" void kernel_launch(void* const* d_in, const int* in_sizes, int n_in,
                              void* d_out, int out_size, void* d_ws, size_t ws_size,
                              hipStream_t stream) {
    // inputs: 0:h [N,64] 1:q 2:edge_index [2,E] int 3:edge_batch [E]
    //         4:W1 5:b1 6:W2 7:b2 8:ln_gamma 9:ln_beta
    const int* edge_index = (const int*)d_in[2];
    const float* ln_beta  = (const float*)d_in[9];
    const int E = in_sizes[3];
    const int N = in_sizes[0] / 64;

    const int* src = edge_index;       // row 0
    const int* dst = edge_index + E;   // row 1

    float* keep_out  = (float*)d_out;       // first E floats: keep (0/1)
    float* score_out = (float*)d_out + E;   // next E floats: scores

    unsigned long long* partials = (unsigned long long*)d_ws;   // NBLK*W u64

    const int W      = (N + RANGES - 1) / RANGES;               // 1563
    const int segLen = (((E + SEGS - 1) / SEGS) + 3) & ~3;      // 25000

    const int block = 256;
    np_write<<<((E + 3) / 4 + block - 1) / block, block, 0, stream>>>(
        src, dst, ln_beta, keep_out, score_out, E);
    np_scan<<<NBLK, block, (size_t)W * sizeof(unsigned long long), stream>>>(
        src, dst, partials, E, W, segLen);
    np_merge<<<(N + block - 1) / block, block, 0, stream>>>(partials, keep_out, N, W);
}

// Round 3
// 117.078 us; speedup vs baseline: 1.1217x; 1.1217x over previous
//
#include <hip/hip_runtime.h>

// NeighborPruning: LayerNorm over a size-1 axis makes every score identically
// ln_beta. All regular edges tie; stable lexsort => per-dst top-3 = the 3
// smallest original edge indices among regular (non-self-loop) edges.
// Self loops kept unconditionally.
//
// R6 structure — R5 was dependent-latency-bound at 2 blocks/CU (occupancy 18%,
// 417 GB/s, 46us). Same LDS-top3 algorithm, 4x TLP and no dependent gather:
//  1) np_write — int4/float4 streaming outputs: score=beta, keep=self?1:0.
//  2) np_scan  — 2048 blocks = 32 dst-ranges x 64 edge-segments (8 blocks/CU,
//     32 waves/CU, ~6 int4-iters/thread). src AND dst loaded as int4
//     unconditionally (self-loop test register-local; no scattered dependent
//     load). Hits (~3%) insert into LDS packed-u64 top-3 via LDS CAS. Flush
//     W=ceil(N/32)=1563 slots/block to workspace (25.6 MB total, coalesced).
//  3) np_merge — one thread per dst: fold 64 partial triples (coalesced,
//     sentinel-skip fast path), scatter keep=1 to the <=3 winners.
//
// Harness floor: two 256MB workspace-poison fills (~84us) are inside the
// timed graph and untouchable; user-kernel budget is what we optimize.
//
// Workspace: NBLK * W * 8B = 2048 * 1563 * 8 = 25.6 MB (<< ws_size).
// Edge ids fit 21 bits (E = 400000 < 2^21).

#define SENT21 0x1FFFFFu
#define RANGES 32   // dst ranges (power of 2; W*8B LDS per block)
#define SEGS   64   // edge segments
#define NBLK   (RANGES * SEGS)

__device__ __forceinline__ unsigned long long pack3(unsigned a, unsigned b, unsigned c) {
    return ((unsigned long long)a << 42) | ((unsigned long long)b << 21) | (unsigned long long)c;
}

// Monotone top-3 insert into an LDS slot. Fields only decrease => stale plain
// reads are direction-safe (an old value has a LARGER s2, so we never wrongly
// skip; the CAS retry corrects).
__device__ __forceinline__ void lds_insert(unsigned long long* slot, unsigned v) {
    unsigned long long cur = *slot;
    while (v < ((unsigned)cur & SENT21)) {           // v < s2 ?
        unsigned s0 = (unsigned)(cur >> 42) & SENT21;
        unsigned s1 = (unsigned)(cur >> 21) & SENT21;
        unsigned n0, n1, n2;
        if (v < s0)      { n0 = v;  n1 = s0; n2 = s1; }
        else if (v < s1) { n0 = s0; n1 = v;  n2 = s1; }
        else             { n0 = s0; n1 = s1; n2 = v;  }
        unsigned long long prev = atomicCAS(slot, cur, pack3(n0, n1, n2));
        if (prev == cur) break;                      // installed
        cur = prev;                                  // lost race; recheck
    }
}

// Streaming outputs: scores = beta, keep = self-loop ? 1 : 0.
__global__ void np_write(const int* __restrict__ src,
                         const int* __restrict__ dst,
                         const float* __restrict__ ln_beta,
                         float* __restrict__ keep_out,
                         float* __restrict__ score_out, int E) {
    int e = (blockIdx.x * blockDim.x + threadIdx.x) * 4;
    if (e >= E) return;
    float beta = ln_beta[0];
    if (e + 4 <= E) {
        int4 s4 = *reinterpret_cast<const int4*>(src + e);
        int4 d4 = *reinterpret_cast<const int4*>(dst + e);
        float4 k4 = make_float4(s4.x == d4.x ? 1.f : 0.f,
                                s4.y == d4.y ? 1.f : 0.f,
                                s4.z == d4.z ? 1.f : 0.f,
                                s4.w == d4.w ? 1.f : 0.f);
        *reinterpret_cast<float4*>(keep_out + e)  = k4;
        *reinterpret_cast<float4*>(score_out + e) = make_float4(beta, beta, beta, beta);
    } else {
        for (int i = e; i < E; ++i) {
            keep_out[i]  = (src[i] == dst[i]) ? 1.f : 0.f;
            score_out[i] = beta;
        }
    }
}

// Block (r, sg): scan segment sg's src/dst with int4 loads, keep LDS top-3
// for dst range r, flush packed slots to partials[blockIdx][0..W).
__global__ void np_scan(const int* __restrict__ src,
                        const int* __restrict__ dst,
                        unsigned long long* __restrict__ partials,
                        int E, int W, int segLen) {
    extern __shared__ unsigned long long lsl[];
    const int r  = blockIdx.x & (RANGES - 1);
    const int sg = blockIdx.x >> 5;                  // log2(RANGES) = 5
    const int lo = r * W;

    for (int w = threadIdx.x; w < W; w += blockDim.x) lsl[w] = ~0ULL;
    __syncthreads();

    const int e0 = sg * segLen;
    const int e1 = min(E, e0 + segLen);

    int e = e0 + (int)threadIdx.x * 4;
    for (; e + 3 < e1; e += (int)blockDim.x * 4) {
        int4 d4 = *reinterpret_cast<const int4*>(dst + e);
        int4 s4 = *reinterpret_cast<const int4*>(src + e);   // independent, coalesced
        #pragma unroll
        for (int k = 0; k < 4; ++k) {
            int d = (&d4.x)[k];
            unsigned rel = (unsigned)(d - lo);
            if (rel < (unsigned)W && (&s4.x)[k] != d)        // in-range, non-self
                lds_insert(&lsl[rel], (unsigned)(e + k));
        }
    }
    // scalar tail (only when segment length % 4 != 0)
    for (; e < e1; ++e) {
        int d = dst[e];
        unsigned rel = (unsigned)(d - lo);
        if (rel < (unsigned)W && src[e] != d)
            lds_insert(&lsl[rel], (unsigned)e);
    }

    __syncthreads();
    unsigned long long* out = partials + (size_t)blockIdx.x * (size_t)W;
    for (int w = threadIdx.x; w < W; w += blockDim.x) out[w] = lsl[w];
}

// One thread per dst: merge SEGS sorted triples, scatter keep=1 to winners.
__global__ void np_merge(const unsigned long long* __restrict__ partials,
                         float* __restrict__ keep_out, int N, int W) {
    int d = blockIdx.x * blockDim.x + threadIdx.x;
    if (d >= N) return;
    int r   = d / W;
    int rel = d - r * W;
    unsigned t0 = SENT21, t1 = SENT21, t2 = SENT21;
    for (int sg = 0; sg < SEGS; ++sg) {
        unsigned long long st = partials[(size_t)(sg * RANGES + r) * (size_t)W + rel];
        unsigned a0 = (unsigned)(st >> 42) & SENT21;
        if (a0 >= t2) continue;                      // sorted triple: all >= t2
        if (a0 < t0)      { t2 = t1; t1 = t0; t0 = a0; }
        else if (a0 < t1) { t2 = t1; t1 = a0; }
        else              { t2 = a0; }
        unsigned a1 = (unsigned)(st >> 21) & SENT21;
        if (a1 >= t2) continue;
        if (a1 < t0)      { t2 = t1; t1 = t0; t0 = a1; }
        else if (a1 < t1) { t2 = t1; t1 = a1; }
        else              { t2 = a1; }
        unsigned a2 = (unsigned)st & SENT21;
        if (a2 >= t2) continue;
        if (a2 < t0)      { t2 = t1; t1 = t0; t0 = a2; }
        else if (a2 < t1) { t2 = t1; t1 = a2; }
        else              { t2 = a2; }
    }
    if (t0 != SENT21) keep_out[t0] = 1.f;
    if (t1 != SENT21) keep_out[t1] = 1.f;
    if (t2 != SENT21) keep_out[t2] = 1.f;
}

extern "C" void kernel_launch(void* const* d_in, const int* in_sizes, int n_in,
                              void* d_out, int out_size, void* d_ws, size_t ws_size,
                              hipStream_t stream) {
    // inputs: 0:h [N,64] 1:q 2:edge_index [2,E] int 3:edge_batch [E]
    //         4:W1 5:b1 6:W2 7:b2 8:ln_gamma 9:ln_beta
    const int* edge_index = (const int*)d_in[2];
    const float* ln_beta  = (const float*)d_in[9];
    const int E = in_sizes[3];
    const int N = in_sizes[0] / 64;

    const int* src = edge_index;       // row 0
    const int* dst = edge_index + E;   // row 1

    float* keep_out  = (float*)d_out;       // first E floats: keep (0/1)
    float* score_out = (float*)d_out + E;   // next E floats: scores

    unsigned long long* partials = (unsigned long long*)d_ws;   // NBLK*W u64

    const int W      = (N + RANGES - 1) / RANGES;               // 1563
    const int segLen = (((E + SEGS - 1) / SEGS) + 3) & ~3;      // 6252

    const int block = 256;
    np_write<<<((E + 3) / 4 + block - 1) / block, block, 0, stream>>>(
        src, dst, ln_beta, keep_out, score_out, E);
    np_scan<<<NBLK, block, (size_t)W * sizeof(unsigned long long), stream>>>(
        src, dst, partials, E, W, segLen);
    np_merge<<<(N + block - 1) / block, block, 0, stream>>>(partials, keep_out, N, W);
}

// Round 4
// 96.799 us; speedup vs baseline: 1.3566x; 1.2095x over previous
//
#include <hip/hip_runtime.h>

// NeighborPruning: LayerNorm over a size-1 axis makes every score identically
// ln_beta. All regular edges tie; stable lexsort => per-dst top-3 = the 3
// smallest original edge indices among regular (non-self-loop) edges.
// Self loops kept unconditionally.
//
// R7 structure — bucket-scatter replaces broadcast-scan + dense-partials merge
// (R6's remaining ~29us user time: scan re-read the edge list 32x via L2, and
// merge re-read 25.6MB of ~88%-sentinel partials):
//  1) np_bucket — 782 blocks x 256 thr, 512 edges each, int2 loads. Writes
//     keep=self?1:0 and score=beta (absorbs old np_write), and scatters each
//     non-self edge ONCE as a packed u32 (rel<<21|e) into bucket
//     buf[range][blk][CAP=24] using an LDS per-range counter. Bucket overflow
//     (Binom(512,1/98) mean 5.2, CAP=24 ~ 9 sigma) goes exactly to a per-block
//     overflow list (normally empty).
//  2) np_top3  — one block per range (98 blocks x 1024 thr): stages per-block
//     counts in LDS, reads its range's compacted entries (contiguous), builds
//     the final per-dst top-3 in LDS (W=512 packed-u64 slots, LDS CAS), drains
//     the overflow list (normally a no-op), scatters keep=1 to winners.
//
// Harness floor: two 256MB workspace-poison fills (~88us) are inside the
// timed graph and untouchable; user-kernel time is the optimizable part.
//
// Workspace: ovf 3.2MB + buf 7.4MB + cnt 0.3MB + ovfcnt 3KB ~= 11MB << ws.
// Edge ids fit 21 bits (E = 400000 < 2^21); rel fits 9 bits (W = 512).

#define SENT21 0x1FFFFFu
#define WSLOT  512   // dsts per range (pow2: r = d>>9, rel = d&511)
#define CAP    24    // bucket capacity per (range, passA-block)
#define EPB    512   // edges per pass-A block
#define MAXRANGES 128

__device__ __forceinline__ unsigned long long pack3(unsigned a, unsigned b, unsigned c) {
    return ((unsigned long long)a << 42) | ((unsigned long long)b << 21) | (unsigned long long)c;
}

// Monotone top-3 insert into an LDS slot. Fields only decrease => stale plain
// reads are direction-safe; the CAS retry corrects lost races.
__device__ __forceinline__ void lds_insert(unsigned long long* slot, unsigned v) {
    unsigned long long cur = *slot;
    while (v < ((unsigned)cur & SENT21)) {           // v < s2 ?
        unsigned s0 = (unsigned)(cur >> 42) & SENT21;
        unsigned s1 = (unsigned)(cur >> 21) & SENT21;
        unsigned n0, n1, n2;
        if (v < s0)      { n0 = v;  n1 = s0; n2 = s1; }
        else if (v < s1) { n0 = s0; n1 = v;  n2 = s1; }
        else             { n0 = s0; n1 = s1; n2 = v;  }
        unsigned long long prev = atomicCAS(slot, cur, pack3(n0, n1, n2));
        if (prev == cur) break;                      // installed
        cur = prev;                                  // lost race; recheck
    }
}

// Pass A: stream 512 edges/block; write keep/score; compact non-self edges
// into per-(range, block) buckets.
__global__ void np_bucket(const int* __restrict__ src,
                          const int* __restrict__ dst,
                          const float* __restrict__ ln_beta,
                          float* __restrict__ keep_out,
                          float* __restrict__ score_out,
                          unsigned* __restrict__ buf,
                          unsigned* __restrict__ cnt,
                          unsigned long long* __restrict__ ovf,
                          unsigned* __restrict__ ovfcnt,
                          int E, int ablk, int nranges) {
    __shared__ unsigned lcnt[MAXRANGES];
    __shared__ unsigned lovf;
    const int blk = blockIdx.x, tid = threadIdx.x;
    for (int i = tid; i < nranges; i += blockDim.x) lcnt[i] = 0;
    if (tid == 0) lovf = 0;
    __syncthreads();

    const int e0 = blk * EPB;
    const int e1 = min(E, e0 + EPB);
    const float beta = ln_beta[0];

    auto proc = [&](int s, int d, int e) {
        if (s != d) {
            unsigned r   = (unsigned)d >> 9;
            unsigned rel = (unsigned)d & (WSLOT - 1);
            unsigned pk  = (rel << 21) | (unsigned)e;
            unsigned off = atomicAdd(&lcnt[r], 1u);
            if (off < CAP) {
                buf[((size_t)r * ablk + blk) * CAP + off] = pk;
            } else {
                unsigned j = atomicAdd(&lovf, 1u);
                ovf[(size_t)blk * EPB + j] = ((unsigned long long)r << 32) | pk;
            }
        }
    };

    int e = e0 + tid * 2;
    if (e + 1 < e1) {
        int2 s2 = *reinterpret_cast<const int2*>(src + e);
        int2 d2 = *reinterpret_cast<const int2*>(dst + e);
        *reinterpret_cast<float2*>(keep_out + e) =
            make_float2(s2.x == d2.x ? 1.f : 0.f, s2.y == d2.y ? 1.f : 0.f);
        *reinterpret_cast<float2*>(score_out + e) = make_float2(beta, beta);
        proc(s2.x, d2.x, e);
        proc(s2.y, d2.y, e + 1);
    } else if (e < e1) {
        int s = src[e], d = dst[e];
        keep_out[e]  = (s == d) ? 1.f : 0.f;
        score_out[e] = beta;
        proc(s, d, e);
    }

    __syncthreads();
    for (int i = tid; i < nranges; i += blockDim.x)
        cnt[(size_t)i * ablk + blk] = min(lcnt[i], (unsigned)CAP);
    if (tid == 0) ovfcnt[blk] = lovf;
}

// Pass B: one block per range. Build final per-dst top-3 in LDS from the
// compacted buckets, drain overflow (normally empty), scatter keep=1.
__global__ __launch_bounds__(1024) void np_top3(
    const unsigned* __restrict__ buf,
    const unsigned* __restrict__ cnt,
    const unsigned long long* __restrict__ ovf,
    const unsigned* __restrict__ ovfcnt,
    float* __restrict__ keep_out, int ablk) {
    __shared__ unsigned long long lsl[WSLOT];
    __shared__ unsigned scnt[1024];
    __shared__ unsigned s_ovf;
    const int r = blockIdx.x, tid = threadIdx.x, nt = blockDim.x;

    for (int w = tid; w < WSLOT; w += nt) lsl[w] = ~0ULL;
    const bool stage = (ablk <= 1024);
    if (stage)
        for (int i = tid; i < ablk; i += nt) scnt[i] = cnt[(size_t)r * ablk + i];
    unsigned myov = 0;
    for (int i = tid; i < ablk; i += nt) myov += ovfcnt[i];
    if (tid == 0) s_ovf = 0;
    __syncthreads();
    if (myov) atomicAdd(&s_ovf, myov);

    const int tot = ablk * CAP;
    const unsigned* base = buf + (size_t)r * ablk * CAP;
    for (int idx = tid; idx < tot; idx += nt) {
        int blk = idx / CAP;                 // const divisor -> magic mul
        int si  = idx - blk * CAP;
        unsigned c = stage ? scnt[blk] : cnt[(size_t)r * ablk + blk];
        if ((unsigned)si < c) {
            unsigned pk = base[idx];         // contiguous, coalesced
            lds_insert(&lsl[pk >> 21], pk & SENT21);
        }
    }
    __syncthreads();                          // also publishes s_ovf

    if (s_ovf) {                              // cold path: exact overflow drain
        for (int blk = 0; blk < ablk; ++blk) {
            unsigned c = ovfcnt[blk];
            for (unsigned i = tid; i < c; i += nt) {
                unsigned long long t = ovf[(size_t)blk * EPB + i];
                if ((unsigned)(t >> 32) == (unsigned)r) {
                    unsigned pk = (unsigned)t;
                    lds_insert(&lsl[pk >> 21], pk & SENT21);
                }
            }
        }
        __syncthreads();
    }

    for (int w = tid; w < WSLOT; w += nt) {
        unsigned long long st = lsl[w];
        unsigned a0 = (unsigned)(st >> 42) & SENT21;
        unsigned a1 = (unsigned)(st >> 21) & SENT21;
        unsigned a2 = (unsigned)st & SENT21;
        if (a0 != SENT21) keep_out[a0] = 1.f;
        if (a1 != SENT21) keep_out[a1] = 1.f;
        if (a2 != SENT21) keep_out[a2] = 1.f;
    }
}

extern "C" void kernel_launch(void* const* d_in, const int* in_sizes, int n_in,
                              void* d_out, int out_size, void* d_ws, size_t ws_size,
                              hipStream_t stream) {
    // inputs: 0:h [N,64] 1:q 2:edge_index [2,E] int 3:edge_batch [E]
    //         4:W1 5:b1 6:W2 7:b2 8:ln_gamma 9:ln_beta
    const int* edge_index = (const int*)d_in[2];
    const float* ln_beta  = (const float*)d_in[9];
    const int E = in_sizes[3];
    const int N = in_sizes[0] / 64;

    const int* src = edge_index;       // row 0
    const int* dst = edge_index + E;   // row 1

    float* keep_out  = (float*)d_out;       // first E floats: keep (0/1)
    float* score_out = (float*)d_out + E;   // next E floats: scores

    const int ablk    = (E + EPB - 1) / EPB;          // 782
    const int nranges = (N + WSLOT - 1) / WSLOT;      // 98  (<= MAXRANGES)

    // workspace layout (u64-aligned first)
    unsigned long long* ovf = (unsigned long long*)d_ws;       // ablk*EPB u64
    unsigned* buf    = (unsigned*)(ovf + (size_t)ablk * EPB);  // nranges*ablk*CAP
    unsigned* cnt    = buf + (size_t)nranges * ablk * CAP;     // nranges*ablk
    unsigned* ovfcnt = cnt + (size_t)nranges * ablk;           // ablk

    np_bucket<<<ablk, 256, 0, stream>>>(src, dst, ln_beta, keep_out, score_out,
                                        buf, cnt, ovf, ovfcnt, E, ablk, nranges);
    np_top3<<<nranges, 1024, 0, stream>>>(buf, cnt, ovf, ovfcnt, keep_out, ablk);
}

// Round 5
// 89.667 us; speedup vs baseline: 1.4646x; 1.0795x over previous
//
#include <hip/hip_runtime.h>

// NeighborPruning: LayerNorm over a size-1 axis makes every score identically
// ln_beta. All regular edges tie; stable lexsort => per-dst top-3 = the 3
// smallest original edge indices among regular (non-self-loop) edges.
// Self loops kept unconditionally.
//
// R8 structure — R7 tuned (R7: 96.8us total = ~85us harness poison fills +
// ~11.8us user). Changes: EPB 512->1024 + int4 loads (ablk 782->391: halves
// pass-B bucket-line probes), WSLOT 512->256 (nranges 98->196: doubles pass-B
// CU utilization, halves per-block inserts). Same proven bucket-scatter +
// LDS-CAS top-3 with exact overflow path.
//  1) np_bucket — 391 blocks x 256 thr, 1024 edges each, int4 loads. Writes
//     keep=self?1:0, score=beta, and scatters each non-self edge once as
//     packed u32 (rel<<21|e) into buf[range][blk][CAP=20] via LDS counters.
//     Overflow (Binom(1024,1/196) mean 5.2, CAP=20 ~ +6.5 sigma) goes exactly
//     to a per-block overflow list (normally empty).
//  2) np_top3  — one block per range (196 blocks x 1024 thr): stages counts,
//     reads live compacted entries (~1 line/bucket), builds per-dst top-3 in
//     LDS (256 packed-u64 slots), drains overflow, scatters keep=1.
//
// Harness floor: two 256MB workspace-poison fills (~85us) inside the timed
// graph are untouchable; user-kernel time is the optimizable part.
//
// Workspace: ovf 3.2MB + buf 6.1MB + cnt 0.3MB + ovfcnt 1.6KB ~= 9.7MB << ws.
// Edge ids fit 21 bits (E = 400000 < 2^21); rel fits 8 bits (WSLOT = 256).

#define SENT21 0x1FFFFFu
#define WSLOT  256   // dsts per range (pow2: r = d>>8, rel = d&255)
#define CAP    20    // bucket capacity per (range, passA-block)
#define EPB    1024  // edges per pass-A block
#define MAXRANGES 256

__device__ __forceinline__ unsigned long long pack3(unsigned a, unsigned b, unsigned c) {
    return ((unsigned long long)a << 42) | ((unsigned long long)b << 21) | (unsigned long long)c;
}

// Monotone top-3 insert into an LDS slot. Fields only decrease => stale plain
// reads are direction-safe; the CAS retry corrects lost races.
__device__ __forceinline__ void lds_insert(unsigned long long* slot, unsigned v) {
    unsigned long long cur = *slot;
    while (v < ((unsigned)cur & SENT21)) {           // v < s2 ?
        unsigned s0 = (unsigned)(cur >> 42) & SENT21;
        unsigned s1 = (unsigned)(cur >> 21) & SENT21;
        unsigned n0, n1, n2;
        if (v < s0)      { n0 = v;  n1 = s0; n2 = s1; }
        else if (v < s1) { n0 = s0; n1 = v;  n2 = s1; }
        else             { n0 = s0; n1 = s1; n2 = v;  }
        unsigned long long prev = atomicCAS(slot, cur, pack3(n0, n1, n2));
        if (prev == cur) break;                      // installed
        cur = prev;                                  // lost race; recheck
    }
}

// Pass A: stream 1024 edges/block with int4 loads; write keep/score; compact
// non-self edges into per-(range, block) buckets.
__global__ void np_bucket(const int* __restrict__ src,
                          const int* __restrict__ dst,
                          const float* __restrict__ ln_beta,
                          float* __restrict__ keep_out,
                          float* __restrict__ score_out,
                          unsigned* __restrict__ buf,
                          unsigned* __restrict__ cnt,
                          unsigned long long* __restrict__ ovf,
                          unsigned* __restrict__ ovfcnt,
                          int E, int ablk, int nranges) {
    __shared__ unsigned lcnt[MAXRANGES];
    __shared__ unsigned lovf;
    const int blk = blockIdx.x, tid = threadIdx.x;
    for (int i = tid; i < nranges; i += blockDim.x) lcnt[i] = 0;
    if (tid == 0) lovf = 0;
    __syncthreads();

    const int e0 = blk * EPB;
    const int e1 = min(E, e0 + EPB);
    const float beta = ln_beta[0];

    auto proc = [&](int s, int d, int e) {
        if (s != d) {
            unsigned r   = (unsigned)d >> 8;
            unsigned rel = (unsigned)d & (WSLOT - 1);
            unsigned pk  = (rel << 21) | (unsigned)e;
            unsigned off = atomicAdd(&lcnt[r], 1u);
            if (off < CAP) {
                buf[((size_t)r * ablk + blk) * CAP + off] = pk;
            } else {
                unsigned j = atomicAdd(&lovf, 1u);
                ovf[(size_t)blk * EPB + j] = ((unsigned long long)r << 32) | pk;
            }
        }
    };

    int e = e0 + tid * 4;
    if (e + 4 <= e1) {
        int4 s4 = *reinterpret_cast<const int4*>(src + e);
        int4 d4 = *reinterpret_cast<const int4*>(dst + e);
        *reinterpret_cast<float4*>(keep_out + e) =
            make_float4(s4.x == d4.x ? 1.f : 0.f, s4.y == d4.y ? 1.f : 0.f,
                        s4.z == d4.z ? 1.f : 0.f, s4.w == d4.w ? 1.f : 0.f);
        *reinterpret_cast<float4*>(score_out + e) = make_float4(beta, beta, beta, beta);
        proc(s4.x, d4.x, e);
        proc(s4.y, d4.y, e + 1);
        proc(s4.z, d4.z, e + 2);
        proc(s4.w, d4.w, e + 3);
    } else {
        for (int i = e; i < e1; ++i) {       // tail (E%4==0: normally unused)
            int s = src[i], d = dst[i];
            keep_out[i]  = (s == d) ? 1.f : 0.f;
            score_out[i] = beta;
            proc(s, d, i);
        }
    }

    __syncthreads();
    for (int i = tid; i < nranges; i += blockDim.x)
        cnt[(size_t)i * ablk + blk] = min(lcnt[i], (unsigned)CAP);
    if (tid == 0) ovfcnt[blk] = lovf;
}

// Pass B: one block per range. Build final per-dst top-3 in LDS from the
// compacted buckets, drain overflow (normally empty), scatter keep=1.
__global__ __launch_bounds__(1024) void np_top3(
    const unsigned* __restrict__ buf,
    const unsigned* __restrict__ cnt,
    const unsigned long long* __restrict__ ovf,
    const unsigned* __restrict__ ovfcnt,
    float* __restrict__ keep_out, int ablk) {
    __shared__ unsigned long long lsl[WSLOT];
    __shared__ unsigned scnt[1024];
    __shared__ unsigned s_ovf;
    const int r = blockIdx.x, tid = threadIdx.x, nt = blockDim.x;

    for (int w = tid; w < WSLOT; w += nt) lsl[w] = ~0ULL;
    const bool stage = (ablk <= 1024);
    if (stage)
        for (int i = tid; i < ablk; i += nt) scnt[i] = cnt[(size_t)r * ablk + i];
    unsigned myov = 0;
    for (int i = tid; i < ablk; i += nt) myov += ovfcnt[i];
    if (tid == 0) s_ovf = 0;
    __syncthreads();
    if (myov) atomicAdd(&s_ovf, myov);

    const int tot = ablk * CAP;
    const unsigned* base = buf + (size_t)r * ablk * CAP;
    for (int idx = tid; idx < tot; idx += nt) {
        int blk = idx / CAP;                 // const divisor -> magic mul
        int si  = idx - blk * CAP;
        unsigned c = stage ? scnt[blk] : cnt[(size_t)r * ablk + blk];
        if ((unsigned)si < c) {
            unsigned pk = base[idx];         // live entries only (~1 line/bucket)
            lds_insert(&lsl[pk >> 21], pk & SENT21);
        }
    }
    __syncthreads();                          // also publishes s_ovf

    if (s_ovf) {                              // cold path: exact overflow drain
        for (int blk = 0; blk < ablk; ++blk) {
            unsigned c = ovfcnt[blk];
            for (unsigned i = tid; i < c; i += nt) {
                unsigned long long t = ovf[(size_t)blk * EPB + i];
                if ((unsigned)(t >> 32) == (unsigned)r) {
                    unsigned pk = (unsigned)t;
                    lds_insert(&lsl[pk >> 21], pk & SENT21);
                }
            }
        }
        __syncthreads();
    }

    for (int w = tid; w < WSLOT; w += nt) {
        unsigned long long st = lsl[w];
        unsigned a0 = (unsigned)(st >> 42) & SENT21;
        unsigned a1 = (unsigned)(st >> 21) & SENT21;
        unsigned a2 = (unsigned)st & SENT21;
        if (a0 != SENT21) keep_out[a0] = 1.f;
        if (a1 != SENT21) keep_out[a1] = 1.f;
        if (a2 != SENT21) keep_out[a2] = 1.f;
    }
}

extern "C" void kernel_launch(void* const* d_in, const int* in_sizes, int n_in,
                              void* d_out, int out_size, void* d_ws, size_t ws_size,
                              hipStream_t stream) {
    // inputs: 0:h [N,64] 1:q 2:edge_index [2,E] int 3:edge_batch [E]
    //         4:W1 5:b1 6:W2 7:b2 8:ln_gamma 9:ln_beta
    const int* edge_index = (const int*)d_in[2];
    const float* ln_beta  = (const float*)d_in[9];
    const int E = in_sizes[3];
    const int N = in_sizes[0] / 64;

    const int* src = edge_index;       // row 0
    const int* dst = edge_index + E;   // row 1

    float* keep_out  = (float*)d_out;       // first E floats: keep (0/1)
    float* score_out = (float*)d_out + E;   // next E floats: scores

    const int ablk    = (E + EPB - 1) / EPB;          // 391
    const int nranges = (N + WSLOT - 1) / WSLOT;      // 196 (<= MAXRANGES)

    // workspace layout (u64-aligned first)
    unsigned long long* ovf = (unsigned long long*)d_ws;       // ablk*EPB u64
    unsigned* buf    = (unsigned*)(ovf + (size_t)ablk * EPB);  // nranges*ablk*CAP
    unsigned* cnt    = buf + (size_t)nranges * ablk * CAP;     // nranges*ablk
    unsigned* ovfcnt = cnt + (size_t)nranges * ablk;           // ablk

    np_bucket<<<ablk, 256, 0, stream>>>(src, dst, ln_beta, keep_out, score_out,
                                        buf, cnt, ovf, ovfcnt, E, ablk, nranges);
    np_top3<<<nranges, 1024, 0, stream>>>(buf, cnt, ovf, ovfcnt, keep_out, ablk);
}